// Round 2
// baseline (221.097 us; speedup 1.0000x reference)
//
#include <hip/hip_runtime.h>

#define IMW 1024
#define IMH 1024
#define NB  8
#define HALF 25
#define STRIP 16
#define NCELL 64

#define W_R ((double)0.2989f)
#define W_G ((double)0.5870f)
#define W_B ((double)0.1140f)
#define INV_AREA (1.0 / 2601.0)

__device__ __forceinline__ int refl(int i, int n) {
    if (i < 0) i = -i;
    if (i >= n) i = 2 * n - 2 - i;
    return i;
}

// 51-window sum at pixel p from inclusive row cumsum C[0..IMW-1], reflect pad.
__device__ __forceinline__ double wsum(const double* __restrict__ C, int p) {
    int a = p + HALF; if (a > IMW - 1) a = IMW - 1;
    int b = p - HALF - 1;
    double s = C[a] - (b >= 0 ? C[b] : 0.0);
    if (p <= HALF - 1)      s += C[HALF - p] - C[0];                        // i<0 mirrored
    if (p >= IMW - HALF)    s += C[IMW - 2] - C[2*IMW - 2 - HALF - 1 - p];  // i>=IMW mirrored
    return s;
}

// init 64 min-cells (all-ones) and 64 max-cells (zero); g>=0 so f32 bit-order == uint order
__global__ void k0_init(unsigned* cells) {
    cells[threadIdx.x] = (threadIdx.x < NCELL) ? 0xFFFFFFFFu : 0u;
}

// One block per image row. Cumsum of gray/gray^2 via register prefix + wave
// shuffle scan, 2-read window sums -> interleaved float2{h1,h2} (f32 store is
// safe: |h|<=51, round err ~2e-6; /2601 after vertical sum -> ~3e-9 rms on m).
// Min/max in f32 (matches ref's f32 gray candidate set; halves bpermute count
// vs f64 shuffles). hp stores packed as float4 = 2 pixels/store.
__global__ __launch_bounds__(256) void k1_rowpass(const float* __restrict__ in,
                                                  float2* __restrict__ hp,
                                                  float* __restrict__ gray,
                                                  unsigned* __restrict__ cells) {
    __shared__ double cs1[IMW];
    __shared__ double cs2[IMW];
    __shared__ double wt1[4], wt2[4];
    __shared__ float bmin[4], bmax[4];
    const int row = blockIdx.x;                 // 0 .. NB*IMH-1
    const long long base = (long long)row * IMW;
    const int t = threadIdx.x;
    const int lane = t & 63, w = t >> 6;

    // 4 consecutive pixels per thread = 12 floats = 3x float4 (48B, 16B-aligned)
    const float4* p4 = (const float4*)(in + base * 3);
    float4 f0 = p4[3*t], f1 = p4[3*t+1], f2 = p4[3*t+2];
    double g0 = (double)f0.x*W_R + (double)f0.y*W_G + (double)f0.z*W_B;
    double g1 = (double)f0.w*W_R + (double)f1.x*W_G + (double)f1.y*W_B;
    double g2 = (double)f1.z*W_R + (double)f1.w*W_G + (double)f2.x*W_B;
    double g3 = (double)f2.y*W_R + (double)f2.z*W_G + (double)f2.w*W_B;
    float gf0 = (float)g0, gf1 = (float)g1, gf2 = (float)g2, gf3 = (float)g3;

    // stage gray (f32) for k2: 16B coalesced store
    ((float4*)(gray + base))[t] = make_float4(gf0, gf1, gf2, gf3);

    double l1_0 = g0, l1_1 = l1_0 + g1, l1_2 = l1_1 + g2, l1_3 = l1_2 + g3;
    double l2_0 = g0*g0, l2_1 = l2_0 + g1*g1, l2_2 = l2_1 + g2*g2, l2_3 = l2_2 + g3*g3;

    // block min/max in f32 (1 bpermute per shuffle instead of 2)
    float lmin = fminf(fminf(gf0, gf1), fminf(gf2, gf3));
    float lmax = fmaxf(fmaxf(gf0, gf1), fmaxf(gf2, gf3));
    for (int off = 32; off; off >>= 1) {
        lmin = fminf(lmin, __shfl_down(lmin, off));
        lmax = fmaxf(lmax, __shfl_down(lmax, off));
    }
    if (lane == 0) { bmin[w] = lmin; bmax[w] = lmax; }

    // wave-level inclusive scan of per-thread totals
    double v1 = l1_3, v2 = l2_3;
    for (int off = 1; off < 64; off <<= 1) {
        double u1 = __shfl_up(v1, off);
        double u2 = __shfl_up(v2, off);
        if (lane >= off) { v1 += u1; v2 += u2; }
    }
    if (lane == 63) { wt1[w] = v1; wt2[w] = v2; }
    __syncthreads();
    double e1 = v1 - l1_3, e2 = v2 - l2_3;   // exclusive prefix within wave
    for (int j = 0; j < w; j++) { e1 += wt1[j]; e2 += wt2[j]; }

    // write inclusive cumsum, 16B stores
    double2* c1 = (double2*)&cs1[4*t];
    double2* c2 = (double2*)&cs2[4*t];
    c1[0] = make_double2(e1 + l1_0, e1 + l1_1);
    c1[1] = make_double2(e1 + l1_2, e1 + l1_3);
    c2[0] = make_double2(e2 + l2_0, e2 + l2_1);
    c2[1] = make_double2(e2 + l2_2, e2 + l2_3);

    if (t == 0) {
        float m0 = fminf(fminf(bmin[0], bmin[1]), fminf(bmin[2], bmin[3]));
        float m1 = fmaxf(fmaxf(bmax[0], bmax[1]), fmaxf(bmax[2], bmax[3]));
        int cell = row & (NCELL - 1);   // adjacent rows -> different cells
        atomicMin(&cells[cell], __float_as_uint(m0));
        atomicMax(&cells[NCELL + cell], __float_as_uint(m1));
    }
    __syncthreads();

    // interleaved {h1,h2}, 2 pixels packed per float4 store (layout unchanged)
    for (int k = 0; k < 2; k++) {
        int p = 2*t + 512*k;
        float4 h = make_float4((float)wsum(cs1, p),   (float)wsum(cs2, p),
                               (float)wsum(cs1, p+1), (float)wsum(cs2, p+1));
        ((float4*)hp)[(base + p) >> 1] = h;
    }
}

// Column pass: 1 column/thread, vertical running 51-window over interleaved hp.
// STRIP=16 -> 2048 blocks = 8 blocks/CU = 32 waves/CU (full occupancy; STRIP=32's
// 16 waves/CU left the dependent load->add chain latency-exposed). Strip-init
// re-reads ((51+2*16)/16 = 5.2 hp-rows/output-row) are L2/LLC hits: hp+gray
// (100 MB) is LLC-resident after k1.
// XCD-swizzled linear grid: batch = id&7 -> one image per XCD; consecutive ids
// walk y-strips so overlapping 51-row windows share L2.
// Sqrt/div-free Sauvola compare: g > m(1+0.2(s/r-1)) <=> A>0 && A^2 r^2 > 0.04 m^2 var.
__global__ __launch_bounds__(256) void k2_colpass(const float* __restrict__ gray,
                                                  const float2* __restrict__ hp,
                                                  const unsigned* __restrict__ cells,
                                                  float* __restrict__ out) {
    __shared__ double sr[2];
    const int t = threadIdx.x;
    if (t < 64) {
        unsigned mn = cells[t];
        unsigned mx = cells[NCELL + t];
        for (int off = 32; off; off >>= 1) {
            unsigned a = __shfl_down(mn, off);
            unsigned b = __shfl_down(mx, off);
            mn = (a < mn) ? a : mn;
            mx = (b > mx) ? b : mx;
        }
        if (t == 0) {
            sr[0] = (double)__uint_as_float(mn);
            sr[1] = (double)__uint_as_float(mx);
        }
    }
    __syncthreads();
    const double r  = 0.5 * (sr[1] - sr[0]);
    const double r2 = r * r;

    const int id   = blockIdx.x;          // 2048 blocks
    const int b    = id & 7;              // batch -> XCD
    const int rest = id >> 3;
    const int ys   = rest & 63;           // y-strip (consecutive on same XCD)
    const int xc   = rest >> 6;           // x quarter (0..3)
    const int x  = xc * 256 + t;          // 1 column per thread
    const int y0 = ys * STRIP;
    const long long ib = (long long)b * IMH * IMW;

    double vx = 0.0, vy = 0.0;            // {h1,h2} running vertical sums (f64 accum)
    #pragma unroll 8
    for (int j = -HALF; j <= HALF; j++) {
        int ry = refl(y0 + j, IMH);
        float2 h = hp[ib + (long long)ry * IMW + x];
        vx += (double)h.x; vy += (double)h.y;
    }

    #pragma unroll 8
    for (int y = y0; y < y0 + STRIP; y++) {
        long long pix = ib + (long long)y * IMW + x;
        double g = (double)gray[pix];

        double m  = vx * INV_AREA;
        double va = fmax(vy * INV_AREA - m * m, 0.0);
        double A  = g - 0.8 * m;
        int o = (A > 0.0) && (A * A * r2 > 0.04 * m * m * va);
        out[pix] = o ? 1.0f : 0.0f;

        int ra = refl(y + HALF + 1, IMH);
        int rs = refl(y - HALF, IMH);
        float2 ha = hp[ib + (long long)ra * IMW + x];
        float2 hs = hp[ib + (long long)rs * IMW + x];
        vx += (double)ha.x - (double)hs.x;
        vy += (double)ha.y - (double)hs.y;
    }
}

extern "C" void kernel_launch(void* const* d_in, const int* in_sizes, int n_in,
                              void* d_out, int out_size, void* d_ws, size_t ws_size,
                              hipStream_t stream) {
    const float* in = (const float*)d_in[0];
    float* out = (float*)d_out;

    unsigned* cells = (unsigned*)d_ws;                          // 2*64 u32
    float2* hp = (float2*)((char*)d_ws + 4096);                 // 67 MB interleaved {h1,h2}
    float* gray = (float*)((char*)d_ws + 4096
                           + (size_t)NB * IMH * IMW * sizeof(float2)); // 33.5 MB staged gray

    hipLaunchKernelGGL(k0_init, dim3(1), dim3(2 * NCELL), 0, stream, cells);
    hipLaunchKernelGGL(k1_rowpass, dim3(NB * IMH), dim3(256), 0, stream,
                       in, hp, gray, cells);
    hipLaunchKernelGGL(k2_colpass, dim3((IMW / 256) * (IMH / STRIP) * NB), dim3(256), 0, stream,
                       gray, hp, cells, out);
}